// Round 17
// baseline (1921.711 us; speedup 1.0000x reference)
//
#include <hip/hip_runtime.h>
#include <stdint.h>
#include <math.h>

// ============================================================================
// POGLM.sample — bit-exact replication of the JAX-CPU reference.
// R17: manual-asm conv loads with COUNTED lgkmcnt waits. R10/R13/R14/R15's
//      load-placement invariance suggests the compiler drains lgkmcnt(0) per
//      chunk (coarse waits) — serializing 8x ~120cy LDS latency per step.
//      Now: ds_read_b128 via inline asm (untracked), s_waitcnt lgkmcnt(8)
//      per chunk (next chunk stays in flight), sched_barrier(0) fences
//      (rule #18). conv-prefix fills the first chunk's latency window.
//      Arithmetic identical to passing R1-R16 (absmax 0.0625).
// Variant knobs:
#define THREEFRY_PARTITIONABLE 1
#define BITS32_XOR 1
#define VSL_FMA 0
#define CONV_FMA 0
#define RAW_BARRIER 1
#define POISSON_BATCH 4   // inline-path batch (MODE 0 fallback)
#define NT_STORES 1
#define J_PRE 8           // precomputed prefix depth
// ============================================================================

#define T_BINS 1024
#define N_SAMP 64
#define N_NEUR 256
#define J_MAX 32
#define LANES (N_SAMP * N_NEUR)  // 16384

// d_ws layout:
#define SUB_BYTES   (T_BINS * 2 * J_MAX * 4)
#define HIST_OFF    SUB_BYTES
#define HIST_BYTES  (20 * LANES * 4)
#define STBL_OFF    (HIST_OFF + HIST_BYTES)

// --- strict (non-contractable) f32 ops ---
static __device__ __forceinline__ float fmul_s(float a, float b) {
#pragma clang fp contract(off)
  return a * b;
}
static __device__ __forceinline__ float fadd_s(float a, float b) {
#pragma clang fp contract(off)
  return a + b;
}
static __device__ __forceinline__ float fsub_s(float a, float b) {
#pragma clang fp contract(off)
  return a - b;
}

#if VSL_FMA
#define MULADD(a, b, c) __builtin_fmaf((a), (b), (c))
#else
#define MULADD(a, b, c) fadd_s(fmul_s((a), (b)), (c))
#endif

// --- Threefry-2x32, 20 rounds (exact JAX semantics) ---
static __device__ __forceinline__ uint32_t rotl(uint32_t v, uint32_t d) {
  return (v << d) | (v >> (32u - d));
}
static __device__ __forceinline__ void threefry2x32(uint32_t k0, uint32_t k1,
                                                    uint32_t x0, uint32_t x1,
                                                    uint32_t& o0, uint32_t& o1) {
  const uint32_t k2 = k0 ^ k1 ^ 0x1BD11BDAu;
  x0 += k0; x1 += k1;
#define TF_RD(r) { x0 += x1; x1 = rotl(x1, r); x1 ^= x0; }
  TF_RD(13u) TF_RD(15u) TF_RD(26u) TF_RD(6u)
  x0 += k1; x1 += k2 + 1u;
  TF_RD(17u) TF_RD(29u) TF_RD(16u) TF_RD(24u)
  x0 += k2; x1 += k0 + 2u;
  TF_RD(13u) TF_RD(15u) TF_RD(26u) TF_RD(6u)
  x0 += k0; x1 += k1 + 3u;
  TF_RD(17u) TF_RD(29u) TF_RD(16u) TF_RD(24u)
  x0 += k1; x1 += k2 + 4u;
  TF_RD(13u) TF_RD(15u) TF_RD(26u) TF_RD(6u)
  x0 += k2; x1 += k0 + 5u;
#undef TF_RD
  o0 = x0; o1 = x1;
}

// --- XLA CPU Cephes expf (GenerateVF32Exp) ---
static __device__ __forceinline__ float xla_expf(float input) {
  float x = fminf(input, 88.3762626647950f);
  x = fmaxf(x, -88.3762626647949f);
  float fx = floorf(MULADD(x, 1.44269504088896341f, 0.5f));
  float tmp = fmul_s(0.693359375f, fx);
  float z = fmul_s(-2.12194440e-4f, fx);
  x = fsub_s(x, tmp);
  x = fsub_s(x, z);
  z = fmul_s(x, x);
  float y = MULADD(x, 1.9875691500e-4f, 1.3981999507e-3f);
  y = MULADD(y, x, 8.3334519073e-3f);
  y = MULADD(y, x, 4.1665795894e-2f);
  y = MULADD(y, x, 1.6666665459e-1f);
  y = MULADD(y, x, 5.0000001201e-1f);
  y = MULADD(y, z, x);
  y = fadd_s(1.0f, y);
  int n = (int)fx;
  float p2n = __int_as_float((uint32_t)(n + 127) << 23);
  float res = fmul_s(y, p2n);
  return fmaxf(res, input);
}

// --- XLA CPU Cephes logf (GenerateVF32Log); u in {0} U [2^-23, 1) here ---
static __device__ __forceinline__ float xla_logf(float u) {
  if (u == 0.0f) return -INFINITY;
  uint32_t b = __float_as_uint(u);
  float e = (float)((int)(b >> 23) - 127) + 1.0f;
  float m = __uint_as_float((b & 0x007fffffu) | 0x3f000000u);
  if (m < 0.707106781186547524f) {
    e = fsub_s(e, 1.0f);
    m = fadd_s(m, m);
  }
  m = fsub_s(m, 1.0f);
  float z = fmul_s(m, m);
  float y = MULADD(m, 7.0376836292e-2f, -1.1514610310e-1f);
  y = MULADD(y, m, 1.1676998740e-1f);
  y = MULADD(y, m, -1.2420140846e-1f);
  y = MULADD(y, m, 1.4249322787e-1f);
  y = MULADD(y, m, -1.6668057665e-1f);
  y = MULADD(y, m, 2.0000714765e-1f);
  y = MULADD(y, m, -2.4999993993e-1f);
  y = MULADD(y, m, 3.3333331174e-1f);
  y = fmul_s(y, m);
  y = fmul_s(y, z);
  y = MULADD(e, -2.12194440e-4f, y);
  y = MULADD(z, -0.5f, y);
  m = fadd_s(m, y);
  m = MULADD(e, 0.693359375f, m);
  return m;
}

// Shared S-prefix computation: 8 draws for (tt, ln), byte-identical chain.
static __device__ __forceinline__ void stable_body(
    const uint32_t* __restrict__ sub, float* __restrict__ dst8,
    int tt, int ln) {
  float S = 0.0f;
  float v[J_PRE];
#pragma unroll
  for (int j = 0; j < J_PRE; ++j) {
    const uint32_t k0 = sub[(size_t)tt * (2 * J_MAX) + 2 * j];
    const uint32_t k1 = sub[(size_t)tt * (2 * J_MAX) + 2 * j + 1];
    uint32_t o0, o1;
    threefry2x32(k0, k1, 0u, (uint32_t)ln, o0, o1);
#if BITS32_XOR
    const uint32_t bits = o0 ^ o1;
#else
    const uint32_t bits = o1;
#endif
    const float u = __uint_as_float((bits >> 9) | 0x3f800000u) - 1.0f;
    S = fadd_s(S, xla_logf(u));
    v[j] = S;
  }
  float4* dst = reinterpret_cast<float4*>(dst8);
  dst[0] = make_float4(v[0], v[1], v[2], v[3]);
  dst[1] = make_float4(v[4], v[5], v[6], v[7]);
}

// ============================================================================
// Kernel 1: per-time-step subkey chains. sub layout: [t][j][2] u32.
// ============================================================================
__global__ void poglm_subkeys(uint32_t* __restrict__ sub) {
  int t = blockIdx.x * blockDim.x + threadIdx.x;
  if (t >= T_BINS) return;
  uint32_t kt0, kt1;
#if THREEFRY_PARTITIONABLE
  threefry2x32(0u, 1u, 0u, (uint32_t)t, kt0, kt1);
#else
  {
    uint32_t i0 = 2u * t, i1 = 2u * t + 1u, a0, a1, b0, b1;
    if (i0 < 1024u) { threefry2x32(0u, 1u, i0, i0 + 1024u, a0, a1); kt0 = a0; }
    else            { threefry2x32(0u, 1u, i0 - 1024u, i0, a0, a1); kt0 = a1; }
    if (i1 < 1024u) { threefry2x32(0u, 1u, i1, i1 + 1024u, b0, b1); kt1 = b0; }
    else            { threefry2x32(0u, 1u, i1 - 1024u, i1, b0, b1); kt1 = b1; }
  }
#endif
  uint32_t r0 = kt0, r1 = kt1;
  for (int j = 0; j < J_MAX; ++j) {
    uint32_t s0, s1, n0, n1;
#if THREEFRY_PARTITIONABLE
    threefry2x32(r0, r1, 0u, 1u, s0, s1);
    threefry2x32(r0, r1, 0u, 0u, n0, n1);
#else
    uint32_t p00, p01, p10, p11;
    threefry2x32(r0, r1, 0u, 2u, p00, p01);
    threefry2x32(r0, r1, 1u, 3u, p10, p11);
    n0 = p00; n1 = p10;
    s0 = p01; s1 = p11;
#endif
    sub[(size_t)t * (2 * J_MAX) + 2 * j + 0] = s0;
    sub[(size_t)t * (2 * J_MAX) + 2 * j + 1] = s1;
    r0 = n0; r1 = n1;
  }
}

// ============================================================================
// Kernel 1b: standalone S-prefix table — used only for chunk 0.
// ============================================================================
__global__ __launch_bounds__(256)
void poglm_stable(const uint32_t* __restrict__ sub, float* __restrict__ S8,
                  int t0) {
  const int g  = blockIdx.x * 256 + threadIdx.x;
  const int tt = t0 + g / LANES;
  const int ln = g % LANES;
  stable_body(sub, S8 + (size_t)g * J_PRE, tt, ln);
}

// ---- 64 x float4 = 256 AGPR-resident weights --------------------------------
#define FOR64(M) \
  M(0) M(1) M(2) M(3) M(4) M(5) M(6) M(7) M(8) M(9) M(10) M(11) M(12) M(13) \
  M(14) M(15) M(16) M(17) M(18) M(19) M(20) M(21) M(22) M(23) M(24) M(25)   \
  M(26) M(27) M(28) M(29) M(30) M(31) M(32) M(33) M(34) M(35) M(36) M(37)   \
  M(38) M(39) M(40) M(41) M(42) M(43) M(44) M(45) M(46) M(47) M(48) M(49)   \
  M(50) M(51) M(52) M(53) M(54) M(55) M(56) M(57) M(58) M(59) M(60) M(61)   \
  M(62) M(63)

#define WDECL(i) float wA##i, wB##i, wC##i, wD##i;

#define WLOADPIN(i)                                                          \
  { const float4 v_ = w4[i];                                                 \
    asm volatile("v_accvgpr_write_b32 %0, %1" : "=a"(wA##i) : "v"(v_.x));    \
    asm volatile("v_accvgpr_write_b32 %0, %1" : "=a"(wB##i) : "v"(v_.y));    \
    asm volatile("v_accvgpr_write_b32 %0, %1" : "=a"(wC##i) : "v"(v_.z));    \
    asm volatile("v_accvgpr_write_b32 %0, %1" : "=a"(wD##i) : "v"(v_.w)); }

// NON-volatile AGPR read, LICM-blocked by dummy loop-variant operand.
#define AGET(dst, w)                                                         \
  asm("v_accvgpr_read_b32 %0, %1" : "=v"(dst) : "a"(w), "v"(t));

// Quad: 4 AGPR reads + 4 ascending-k fused FMAs (chain bit-locked by zacc).
#define QUAD(cvreg, i)                                                       \
  { float ta_, tb_, tc_, td_;                                                \
    AGET(ta_, wA##i) AGET(tb_, wB##i) AGET(tc_, wC##i) AGET(td_, wD##i)      \
    zacc = __builtin_fmaf(cvreg.x, ta_, zacc);                               \
    zacc = __builtin_fmaf(cvreg.y, tb_, zacc);                               \
    zacc = __builtin_fmaf(cvreg.z, tc_, zacc);                               \
    zacc = __builtin_fmaf(cvreg.w, td_, zacc); }

// Manual ds_read_b128 (untracked by compiler) + counted lgkmcnt waits.
#define DSRD_(dst, OFF)                                                      \
  asm volatile("ds_read_b128 %0, %1 offset:" #OFF                            \
               : "=v"(dst) : "v"(lds_base))
#define DSRD(dst, OFF) DSRD_(dst, OFF)

#define LGKM_(N) asm volatile("s_waitcnt lgkmcnt(" #N ")" ::: "memory")
#define LGKM(N) LGKM_(N); __builtin_amdgcn_sched_barrier(0);

#define DS8A(o0,o1,o2,o3,o4,o5,o6,o7)                                        \
  DSRD(cvA0,o0); DSRD(cvA1,o1); DSRD(cvA2,o2); DSRD(cvA3,o3);                \
  DSRD(cvA4,o4); DSRD(cvA5,o5); DSRD(cvA6,o6); DSRD(cvA7,o7);
#define DS8B(o0,o1,o2,o3,o4,o5,o6,o7)                                        \
  DSRD(cvB0,o0); DSRD(cvB1,o1); DSRD(cvB2,o2); DSRD(cvB3,o3);                \
  DSRD(cvB4,o4); DSRD(cvB5,o5); DSRD(cvB6,o6); DSRD(cvB7,o7);
#define QC_A(i0,i1,i2,i3,i4,i5,i6,i7)                                        \
  QUAD(cvA0,i0) QUAD(cvA1,i1) QUAD(cvA2,i2) QUAD(cvA3,i3)                    \
  QUAD(cvA4,i4) QUAD(cvA5,i5) QUAD(cvA6,i6) QUAD(cvA7,i7)
#define QC_B(i0,i1,i2,i3,i4,i5,i6,i7)                                        \
  QUAD(cvB0,i0) QUAD(cvB1,i1) QUAD(cvB2,i2) QUAD(cvB3,i3)                    \
  QUAD(cvB4,i4) QUAD(cvB5,i5) QUAD(cvB6,i6) QUAD(cvB7,i7)

// ============================================================================
// Kernel 2 (fused): blocks [0,64) = main simulation over [t0,t1) using S8_in;
// blocks [64, 64+nstb) = S-table for [tb0, tb0+chunkT) into S8_out.
// ============================================================================
template <int MODE>
__global__ __launch_bounds__(256, 1)
void poglm_fused(const float* __restrict__ basis, const float* __restrict__ weight,
                 const float* __restrict__ bias, const uint32_t* __restrict__ sub,
                 float* __restrict__ out, const float* __restrict__ S8_in,
                 float* __restrict__ S8_out, int tb0,
                 float* __restrict__ histws, int t0, int t1) {
  if (MODE == 1 && blockIdx.x >= N_SAMP) {
    const int g  = (blockIdx.x - N_SAMP) * 256 + threadIdx.x;
    const int tt = tb0 + g / LANES;
    const int ln = g % LANES;
    stable_body(sub, S8_out + (size_t)g * J_PRE, tt, ln);
    return;
  }

  __builtin_amdgcn_s_setprio(1);

  __shared__ alignas(16) float convb[2][N_NEUR];
  __shared__ uint32_t skb[2][2 * J_MAX];
  __shared__ float fb_lds[20];

  const int s = blockIdx.x;
  const int n = threadIdx.x;

  if (n < 20) fb_lds[n] = basis[19 - n];
  const float bias_n = bias[n];

  // Whole weight row (256 scalars) resident in AGPRs.
  const float4* __restrict__ w4 =
      reinterpret_cast<const float4*>(weight + (size_t)n * N_NEUR);
  FOR64(WDECL)
  FOR64(WLOADPIN)

  const uint32_t idx = (uint32_t)(s * N_NEUR + n);

  float hist[20];
  if (t0 == 0) {
#pragma unroll
    for (int i = 0; i < 20; ++i) hist[i] = 0.0f;
  } else {
#pragma unroll
    for (int i = 0; i < 20; ++i) hist[i] = histws[i * LANES + idx];
  }

  const size_t plane = (size_t)N_SAMP * T_BINS * N_NEUR;
  float* __restrict__ out_spk = out + 0 * plane + (size_t)s * T_BINS * N_NEUR + n;
  float* __restrict__ out_cnv = out + 1 * plane + (size_t)s * T_BINS * N_NEUR + n;
  float* __restrict__ out_rte = out + 2 * plane + (size_t)s * T_BINS * N_NEUR + n;

  uint32_t skreg = 0;
  float4 sc0, sc1;
  if constexpr (MODE == 0) {
    if (n < 2 * J_MAX) skreg = sub[(size_t)t0 * (2 * J_MAX) + n];
  } else {
    const float4* p = reinterpret_cast<const float4*>(S8_in + (size_t)idx * J_PRE);
    sc0 = p[0]; sc1 = p[1];
  }

  __syncthreads();  // fb_lds visible

  float fbr[20];
#pragma unroll
  for (int w = 0; w < 20; ++w) fbr[w] = fb_lds[w];

  // conv for step t0: full ascending-w chain (bit-exact prologue).
  float conv = 0.0f;
#pragma unroll
  for (int w = 0; w < 20; ++w) {
#if CONV_FMA
    conv = __builtin_fmaf(fbr[w], hist[w], conv);
#else
    conv = fadd_s(conv, fmul_s(fbr[w], hist[w]));
#endif
  }

  for (int t = t0; t < t1; ++t) {
    const int buf = t & 1;
    float* __restrict__ convbuf = convb[buf];

    const float conv_cur = conv;
    convbuf[n] = conv_cur;

    float4 sn0, sn1;
    if constexpr (MODE == 0) {
      uint32_t* __restrict__ skbuf = skb[buf];
      if (n < 2 * J_MAX) {
        skbuf[n] = skreg;
        const int tn = (t + 1 < t1) ? t + 1 : t;
        skreg = sub[(size_t)tn * (2 * J_MAX) + n];
      }
    } else {
      const int tn = (t + 1 < t1) ? t + 1 : t;
      const float4* p = reinterpret_cast<const float4*>(
          S8_in + ((size_t)(tn - t0) * LANES + idx) * J_PRE);
      sn0 = p[0]; sn1 = p[1];
    }

#if RAW_BARRIER
    asm volatile("s_waitcnt lgkmcnt(0)\n\ts_barrier" ::: "memory");
#else
    __syncthreads();
#endif

    // z-phase with manual loads + counted waits. Between the barrier and the
    // end of this block, the ONLY lgkm ops are these 64 asm ds_reads, so the
    // counted lgkmcnt values are exact. FMA chain order bit-locked by zacc.
    float zacc = 0.0f;
    float cp = 0.0f;
    {
      const uint32_t lds_base = (uint32_t)(uintptr_t)convbuf;
      float4 cvA0, cvA1, cvA2, cvA3, cvA4, cvA5, cvA6, cvA7;
      float4 cvB0, cvB1, cvB2, cvB3, cvB4, cvB5, cvB6, cvB7;
      DS8A(0,16,32,48,64,80,96,112)            // chunk 0 -> A
      DS8B(128,144,160,176,192,208,224,240)    // chunk 1 -> B

      // conv prefix for next step fills chunk 0's latency window.
#pragma unroll
      for (int w = 0; w < 19; ++w) {
#if CONV_FMA
        cp = __builtin_fmaf(fbr[w], hist[w + 1], cp);
#else
        cp = fadd_s(cp, fmul_s(fbr[w], hist[w + 1]));
#endif
      }

      LGKM(8)  QC_A(0,1,2,3,4,5,6,7)
      DS8A(256,272,288,304,320,336,352,368)    // chunk 2 -> A
      LGKM(8)  QC_B(8,9,10,11,12,13,14,15)
      DS8B(384,400,416,432,448,464,480,496)    // chunk 3 -> B
      LGKM(8)  QC_A(16,17,18,19,20,21,22,23)
      DS8A(512,528,544,560,576,592,608,624)    // chunk 4 -> A
      LGKM(8)  QC_B(24,25,26,27,28,29,30,31)
      DS8B(640,656,672,688,704,720,736,752)    // chunk 5 -> B
      LGKM(8)  QC_A(32,33,34,35,36,37,38,39)
      DS8A(768,784,800,816,832,848,864,880)    // chunk 6 -> A
      LGKM(8)  QC_B(40,41,42,43,44,45,46,47)
      DS8B(896,912,928,944,960,976,992,1008)   // chunk 7 -> B
      LGKM(8)  QC_A(48,49,50,51,52,53,54,55)
      LGKM(0)  QC_B(56,57,58,59,60,61,62,63)
    }
    const float zb = fadd_s(zacc, bias_n);

    // lam = 1 / (1 + exp(-z))
    const float lam = 1.0f / fadd_s(1.0f, xla_expf(-zb));
    const float neg_lam = -lam;

    int r = 0;
    if constexpr (MODE == 1) {
      r = (sc0.x > neg_lam) + (sc0.y > neg_lam) + (sc0.z > neg_lam) +
          (sc0.w > neg_lam) + (sc1.x > neg_lam) + (sc1.y > neg_lam) +
          (sc1.z > neg_lam) + (sc1.w > neg_lam);
      if (__builtin_expect(sc1.w > neg_lam, 0)) {
        float S = sc1.w;
#pragma unroll 1
        for (int j = J_PRE; j < J_MAX; ++j) {
          const uint32_t k0 = sub[(size_t)t * (2 * J_MAX) + 2 * j];
          const uint32_t k1 = sub[(size_t)t * (2 * J_MAX) + 2 * j + 1];
          uint32_t o0, o1;
          threefry2x32(k0, k1, 0u, idx, o0, o1);
#if BITS32_XOR
          const uint32_t bits = o0 ^ o1;
#else
          const uint32_t bits = o1;
#endif
          const float u = __uint_as_float((bits >> 9) | 0x3f800000u) - 1.0f;
          S = fadd_s(S, xla_logf(u));
          if (S > neg_lam) ++r; else break;
        }
      }
    } else {
      uint32_t* __restrict__ skbuf = skb[buf];
      float S = 0.0f;
      bool done = false;
#pragma unroll 1
      for (int jb = 0; jb < J_MAX; jb += POISSON_BATCH) {
        float L[POISSON_BATCH];
#pragma unroll
        for (int q = 0; q < POISSON_BATCH; ++q) {
          const int j = jb + q;
          uint32_t o0, o1;
          threefry2x32(skbuf[2 * j], skbuf[2 * j + 1], 0u, idx, o0, o1);
#if BITS32_XOR
          const uint32_t bits = o0 ^ o1;
#else
          const uint32_t bits = o1;
#endif
          const float u = __uint_as_float((bits >> 9) | 0x3f800000u) - 1.0f;
          L[q] = xla_logf(u);
        }
#pragma unroll
        for (int q = 0; q < POISSON_BATCH; ++q) {
          if (!done) {
            S = fadd_s(S, L[q]);
            if (S > neg_lam) ++r; else done = true;
          }
        }
        if (__all(done)) break;
      }
    }
    const float spk = (float)r;

#pragma unroll
    for (int i = 0; i < 19; ++i) hist[i] = hist[i + 1];
    hist[19] = spk;

    // Next step's conv: prefix + last term (bit-identical composition).
    conv = fadd_s(cp, fmul_s(fbr[19], spk));

    const size_t off = (size_t)t * N_NEUR;
#if NT_STORES
    __builtin_nontemporal_store(spk,      out_spk + off);
    __builtin_nontemporal_store(conv_cur, out_cnv + off);
    __builtin_nontemporal_store(lam,      out_rte + off);
#else
    out_spk[off] = spk;
    out_cnv[off] = conv_cur;
    out_rte[off] = lam;
#endif
    if constexpr (MODE == 1) { sc0 = sn0; sc1 = sn1; }
#if !RAW_BARRIER
    __syncthreads();
#endif
  }

  // Chunk handoff: persist hist for the next launch.
  if (t1 < T_BINS) {
#pragma unroll
    for (int i = 0; i < 20; ++i) histws[i * LANES + idx] = hist[i];
  }
}

extern "C" void kernel_launch(void* const* d_in, const int* in_sizes, int n_in,
                              void* d_out, int out_size, void* d_ws, size_t ws_size,
                              hipStream_t stream) {
  const float* basis  = (const float*)d_in[0];
  const float* weight = (const float*)d_in[1];
  const float* bias   = (const float*)d_in[2];
  float* out = (float*)d_out;
  char* ws = (char*)d_ws;
  uint32_t* sub = (uint32_t*)ws;
  float* histws = (float*)(ws + HIST_OFF);

  hipLaunchKernelGGL(poglm_subkeys, dim3((T_BINS + 255) / 256), dim3(256), 0,
                     stream, sub);

  // Pick chunkT for DOUBLE-buffered S-table.
  int chunkT = 0;
  const int cand[4] = {256, 512, 128, 64};
  for (int ci = 0; ci < 4; ++ci) {
    const size_t bytes = (size_t)cand[ci] * LANES * J_PRE * 4;
    if (STBL_OFF + 2 * bytes <= ws_size) { chunkT = cand[ci]; break; }
  }

  if (chunkT == 0) {
    int sc = 0;
    for (int c = T_BINS; c >= 64; c >>= 1) {
      const size_t bytes = (size_t)c * LANES * J_PRE * 4;
      if (STBL_OFF + bytes <= ws_size) { sc = c; break; }
    }
    if (sc == 0) {
      hipLaunchKernelGGL((poglm_fused<0>), dim3(N_SAMP), dim3(256), 0,
                         stream, basis, weight, bias, sub, out,
                         (const float*)nullptr, (float*)nullptr, 0,
                         histws, 0, T_BINS);
      return;
    }
    float* stbl = (float*)(ws + STBL_OFF);
    for (int t0 = 0; t0 < T_BINS; t0 += sc) {
      hipLaunchKernelGGL(poglm_stable, dim3(sc * (LANES / 256)), dim3(256), 0,
                         stream, sub, stbl, t0);
      hipLaunchKernelGGL((poglm_fused<1>), dim3(N_SAMP), dim3(256), 0,
                         stream, basis, weight, bias, sub, out,
                         (const float*)stbl, (float*)nullptr, 0,
                         histws, t0, t0 + sc);
    }
    return;
  }

  const size_t stbl_bytes = (size_t)chunkT * LANES * J_PRE * 4;
  float* stbl0 = (float*)(ws + STBL_OFF);
  float* stbl1 = (float*)(ws + STBL_OFF + stbl_bytes);
  const int nstb = chunkT * (LANES / 256);
  const int nc = T_BINS / chunkT;

  hipLaunchKernelGGL(poglm_stable, dim3(nstb), dim3(256), 0, stream,
                     sub, stbl0, 0);

  for (int c = 0; c < nc; ++c) {
    const int t0 = c * chunkT, t1 = t0 + chunkT;
    float* cur = (c & 1) ? stbl1 : stbl0;
    float* nxt = (c & 1) ? stbl0 : stbl1;
    const bool more = (c + 1 < nc);
    hipLaunchKernelGGL((poglm_fused<1>),
                       dim3(N_SAMP + (more ? nstb : 0)), dim3(256), 0,
                       stream, basis, weight, bias, sub, out,
                       (const float*)cur, nxt, t1, histws, t0, t1);
  }
}

// Round 18
// 1788.610 us; speedup vs baseline: 1.0744x; 1.0744x over previous
//
#include <hip/hip_runtime.h>
#include <stdint.h>
#include <math.h>

// ============================================================================
// POGLM.sample — bit-exact replication of the JAX-CPU reference.
// R18 = R16 REVERT (best: 1790us total, 446us/main-dispatch).
// R17 lesson: manual ds_read + counted lgkmcnt + sched_barrier fences
// REGRESSED 7% — the compiler's waitcnt/schedule was already near-optimal;
// the z-phase is at its single-wave dependency/issue floor (every
// rearrangement R10-R17 lands 446-494us). Structure:
//   - S-prefix Poisson table (R9): count S_j > -lam, monotone-exact.
//   - Fused kernel (R13): 64 main blocks + stable blocks for chunk c+1 on
//     the otherwise-idle 192 CUs (double-buffered table in ws).
//   - 256 weights/thread in AGPRs (R7/R10 def+use class-locked).
//   - Non-volatile AGPR reads, LICM-blocked by dummy operand (R15).
//   - conv software-pipelined around the z-phase (R16); setprio(1) on main.
// Arithmetic identical to all passing rounds (absmax 0.0625).
// Variant knobs:
#define THREEFRY_PARTITIONABLE 1
#define BITS32_XOR 1
#define VSL_FMA 0
#define CONV_FMA 0
#define RAW_BARRIER 1
#define POISSON_BATCH 4   // inline-path batch (MODE 0 fallback)
#define NT_STORES 1
#define J_PRE 8           // precomputed prefix depth
// ============================================================================

#define T_BINS 1024
#define N_SAMP 64
#define N_NEUR 256
#define J_MAX 32
#define LANES (N_SAMP * N_NEUR)  // 16384

// d_ws layout:
#define SUB_BYTES   (T_BINS * 2 * J_MAX * 4)
#define HIST_OFF    SUB_BYTES
#define HIST_BYTES  (20 * LANES * 4)
#define STBL_OFF    (HIST_OFF + HIST_BYTES)

// --- strict (non-contractable) f32 ops ---
static __device__ __forceinline__ float fmul_s(float a, float b) {
#pragma clang fp contract(off)
  return a * b;
}
static __device__ __forceinline__ float fadd_s(float a, float b) {
#pragma clang fp contract(off)
  return a + b;
}
static __device__ __forceinline__ float fsub_s(float a, float b) {
#pragma clang fp contract(off)
  return a - b;
}

#if VSL_FMA
#define MULADD(a, b, c) __builtin_fmaf((a), (b), (c))
#else
#define MULADD(a, b, c) fadd_s(fmul_s((a), (b)), (c))
#endif

// --- Threefry-2x32, 20 rounds (exact JAX semantics) ---
static __device__ __forceinline__ uint32_t rotl(uint32_t v, uint32_t d) {
  return (v << d) | (v >> (32u - d));
}
static __device__ __forceinline__ void threefry2x32(uint32_t k0, uint32_t k1,
                                                    uint32_t x0, uint32_t x1,
                                                    uint32_t& o0, uint32_t& o1) {
  const uint32_t k2 = k0 ^ k1 ^ 0x1BD11BDAu;
  x0 += k0; x1 += k1;
#define TF_RD(r) { x0 += x1; x1 = rotl(x1, r); x1 ^= x0; }
  TF_RD(13u) TF_RD(15u) TF_RD(26u) TF_RD(6u)
  x0 += k1; x1 += k2 + 1u;
  TF_RD(17u) TF_RD(29u) TF_RD(16u) TF_RD(24u)
  x0 += k2; x1 += k0 + 2u;
  TF_RD(13u) TF_RD(15u) TF_RD(26u) TF_RD(6u)
  x0 += k0; x1 += k1 + 3u;
  TF_RD(17u) TF_RD(29u) TF_RD(16u) TF_RD(24u)
  x0 += k1; x1 += k2 + 4u;
  TF_RD(13u) TF_RD(15u) TF_RD(26u) TF_RD(6u)
  x0 += k2; x1 += k0 + 5u;
#undef TF_RD
  o0 = x0; o1 = x1;
}

// --- XLA CPU Cephes expf (GenerateVF32Exp) ---
static __device__ __forceinline__ float xla_expf(float input) {
  float x = fminf(input, 88.3762626647950f);
  x = fmaxf(x, -88.3762626647949f);
  float fx = floorf(MULADD(x, 1.44269504088896341f, 0.5f));
  float tmp = fmul_s(0.693359375f, fx);
  float z = fmul_s(-2.12194440e-4f, fx);
  x = fsub_s(x, tmp);
  x = fsub_s(x, z);
  z = fmul_s(x, x);
  float y = MULADD(x, 1.9875691500e-4f, 1.3981999507e-3f);
  y = MULADD(y, x, 8.3334519073e-3f);
  y = MULADD(y, x, 4.1665795894e-2f);
  y = MULADD(y, x, 1.6666665459e-1f);
  y = MULADD(y, x, 5.0000001201e-1f);
  y = MULADD(y, z, x);
  y = fadd_s(1.0f, y);
  int n = (int)fx;
  float p2n = __int_as_float((uint32_t)(n + 127) << 23);
  float res = fmul_s(y, p2n);
  return fmaxf(res, input);
}

// --- XLA CPU Cephes logf (GenerateVF32Log); u in {0} U [2^-23, 1) here ---
static __device__ __forceinline__ float xla_logf(float u) {
  if (u == 0.0f) return -INFINITY;
  uint32_t b = __float_as_uint(u);
  float e = (float)((int)(b >> 23) - 127) + 1.0f;
  float m = __uint_as_float((b & 0x007fffffu) | 0x3f000000u);
  if (m < 0.707106781186547524f) {
    e = fsub_s(e, 1.0f);
    m = fadd_s(m, m);
  }
  m = fsub_s(m, 1.0f);
  float z = fmul_s(m, m);
  float y = MULADD(m, 7.0376836292e-2f, -1.1514610310e-1f);
  y = MULADD(y, m, 1.1676998740e-1f);
  y = MULADD(y, m, -1.2420140846e-1f);
  y = MULADD(y, m, 1.4249322787e-1f);
  y = MULADD(y, m, -1.6668057665e-1f);
  y = MULADD(y, m, 2.0000714765e-1f);
  y = MULADD(y, m, -2.4999993993e-1f);
  y = MULADD(y, m, 3.3333331174e-1f);
  y = fmul_s(y, m);
  y = fmul_s(y, z);
  y = MULADD(e, -2.12194440e-4f, y);
  y = MULADD(z, -0.5f, y);
  m = fadd_s(m, y);
  m = MULADD(e, 0.693359375f, m);
  return m;
}

// Shared S-prefix computation: 8 draws for (tt, ln), byte-identical chain.
static __device__ __forceinline__ void stable_body(
    const uint32_t* __restrict__ sub, float* __restrict__ dst8,
    int tt, int ln) {
  float S = 0.0f;
  float v[J_PRE];
#pragma unroll
  for (int j = 0; j < J_PRE; ++j) {
    const uint32_t k0 = sub[(size_t)tt * (2 * J_MAX) + 2 * j];
    const uint32_t k1 = sub[(size_t)tt * (2 * J_MAX) + 2 * j + 1];
    uint32_t o0, o1;
    threefry2x32(k0, k1, 0u, (uint32_t)ln, o0, o1);
#if BITS32_XOR
    const uint32_t bits = o0 ^ o1;
#else
    const uint32_t bits = o1;
#endif
    const float u = __uint_as_float((bits >> 9) | 0x3f800000u) - 1.0f;
    S = fadd_s(S, xla_logf(u));
    v[j] = S;
  }
  float4* dst = reinterpret_cast<float4*>(dst8);
  dst[0] = make_float4(v[0], v[1], v[2], v[3]);
  dst[1] = make_float4(v[4], v[5], v[6], v[7]);
}

// ============================================================================
// Kernel 1: per-time-step subkey chains. sub layout: [t][j][2] u32.
// ============================================================================
__global__ void poglm_subkeys(uint32_t* __restrict__ sub) {
  int t = blockIdx.x * blockDim.x + threadIdx.x;
  if (t >= T_BINS) return;
  uint32_t kt0, kt1;
#if THREEFRY_PARTITIONABLE
  threefry2x32(0u, 1u, 0u, (uint32_t)t, kt0, kt1);
#else
  {
    uint32_t i0 = 2u * t, i1 = 2u * t + 1u, a0, a1, b0, b1;
    if (i0 < 1024u) { threefry2x32(0u, 1u, i0, i0 + 1024u, a0, a1); kt0 = a0; }
    else            { threefry2x32(0u, 1u, i0 - 1024u, i0, a0, a1); kt0 = a1; }
    if (i1 < 1024u) { threefry2x32(0u, 1u, i1, i1 + 1024u, b0, b1); kt1 = b0; }
    else            { threefry2x32(0u, 1u, i1 - 1024u, i1, b0, b1); kt1 = b1; }
  }
#endif
  uint32_t r0 = kt0, r1 = kt1;
  for (int j = 0; j < J_MAX; ++j) {
    uint32_t s0, s1, n0, n1;
#if THREEFRY_PARTITIONABLE
    threefry2x32(r0, r1, 0u, 1u, s0, s1);
    threefry2x32(r0, r1, 0u, 0u, n0, n1);
#else
    uint32_t p00, p01, p10, p11;
    threefry2x32(r0, r1, 0u, 2u, p00, p01);
    threefry2x32(r0, r1, 1u, 3u, p10, p11);
    n0 = p00; n1 = p10;
    s0 = p01; s1 = p11;
#endif
    sub[(size_t)t * (2 * J_MAX) + 2 * j + 0] = s0;
    sub[(size_t)t * (2 * J_MAX) + 2 * j + 1] = s1;
    r0 = n0; r1 = n1;
  }
}

// ============================================================================
// Kernel 1b: standalone S-prefix table — used only for chunk 0.
// ============================================================================
__global__ __launch_bounds__(256)
void poglm_stable(const uint32_t* __restrict__ sub, float* __restrict__ S8,
                  int t0) {
  const int g  = blockIdx.x * 256 + threadIdx.x;
  const int tt = t0 + g / LANES;
  const int ln = g % LANES;
  stable_body(sub, S8 + (size_t)g * J_PRE, tt, ln);
}

// ---- 64 x float4 = 256 AGPR-resident weights --------------------------------
#define FOR64(M) \
  M(0) M(1) M(2) M(3) M(4) M(5) M(6) M(7) M(8) M(9) M(10) M(11) M(12) M(13) \
  M(14) M(15) M(16) M(17) M(18) M(19) M(20) M(21) M(22) M(23) M(24) M(25)   \
  M(26) M(27) M(28) M(29) M(30) M(31) M(32) M(33) M(34) M(35) M(36) M(37)   \
  M(38) M(39) M(40) M(41) M(42) M(43) M(44) M(45) M(46) M(47) M(48) M(49)   \
  M(50) M(51) M(52) M(53) M(54) M(55) M(56) M(57) M(58) M(59) M(60) M(61)   \
  M(62) M(63)

#define WDECL(i) float wA##i, wB##i, wC##i, wD##i;

#define WLOADPIN(i)                                                          \
  { const float4 v_ = w4[i];                                                 \
    asm volatile("v_accvgpr_write_b32 %0, %1" : "=a"(wA##i) : "v"(v_.x));    \
    asm volatile("v_accvgpr_write_b32 %0, %1" : "=a"(wB##i) : "v"(v_.y));    \
    asm volatile("v_accvgpr_write_b32 %0, %1" : "=a"(wC##i) : "v"(v_.z));    \
    asm volatile("v_accvgpr_write_b32 %0, %1" : "=a"(wD##i) : "v"(v_.w)); }

// NON-volatile AGPR read, LICM-blocked by dummy loop-variant operand.
#define AGET(dst, w)                                                         \
  asm("v_accvgpr_read_b32 %0, %1" : "=v"(dst) : "a"(w), "v"(t));

// Quad: 4 AGPR reads + 4 ascending-k fused FMAs (chain bit-locked by zacc).
#define QUAD(cvreg, i)                                                       \
  { float ta_, tb_, tc_, td_;                                                \
    AGET(ta_, wA##i) AGET(tb_, wB##i) AGET(tc_, wC##i) AGET(td_, wD##i)      \
    zacc = __builtin_fmaf(cvreg.x, ta_, zacc);                               \
    zacc = __builtin_fmaf(cvreg.y, tb_, zacc);                               \
    zacc = __builtin_fmaf(cvreg.z, tc_, zacc);                               \
    zacc = __builtin_fmaf(cvreg.w, td_, zacc); }

// Ping-pong cv sets: load chunk c+1's 8 float4 while computing chunk c.
#define ZLOAD_A(i0,i1,i2,i3,i4,i5,i6,i7)                                     \
  cvA0 = convbuf4[i0]; cvA1 = convbuf4[i1]; cvA2 = convbuf4[i2];             \
  cvA3 = convbuf4[i3]; cvA4 = convbuf4[i4]; cvA5 = convbuf4[i5];             \
  cvA6 = convbuf4[i6]; cvA7 = convbuf4[i7];
#define ZLOAD_B(i0,i1,i2,i3,i4,i5,i6,i7)                                     \
  cvB0 = convbuf4[i0]; cvB1 = convbuf4[i1]; cvB2 = convbuf4[i2];             \
  cvB3 = convbuf4[i3]; cvB4 = convbuf4[i4]; cvB5 = convbuf4[i5];             \
  cvB6 = convbuf4[i6]; cvB7 = convbuf4[i7];
#define ZCOMP_A(i0,i1,i2,i3,i4,i5,i6,i7)                                     \
  QUAD(cvA0,i0) QUAD(cvA1,i1) QUAD(cvA2,i2) QUAD(cvA3,i3)                    \
  QUAD(cvA4,i4) QUAD(cvA5,i5) QUAD(cvA6,i6) QUAD(cvA7,i7)
#define ZCOMP_B(i0,i1,i2,i3,i4,i5,i6,i7)                                     \
  QUAD(cvB0,i0) QUAD(cvB1,i1) QUAD(cvB2,i2) QUAD(cvB3,i3)                    \
  QUAD(cvB4,i4) QUAD(cvB5,i5) QUAD(cvB6,i6) QUAD(cvB7,i7)

// ============================================================================
// Kernel 2 (fused): blocks [0,64) = main simulation over [t0,t1) using S8_in;
// blocks [64, 64+nstb) = S-table for [tb0, tb0+chunkT) into S8_out.
// ============================================================================
template <int MODE>
__global__ __launch_bounds__(256, 1)
void poglm_fused(const float* __restrict__ basis, const float* __restrict__ weight,
                 const float* __restrict__ bias, const uint32_t* __restrict__ sub,
                 float* __restrict__ out, const float* __restrict__ S8_in,
                 float* __restrict__ S8_out, int tb0,
                 float* __restrict__ histws, int t0, int t1) {
  if (MODE == 1 && blockIdx.x >= N_SAMP) {
    // stable filler path: priority 0 (default).
    const int g  = (blockIdx.x - N_SAMP) * 256 + threadIdx.x;
    const int tt = tb0 + g / LANES;
    const int ln = g % LANES;
    stable_body(sub, S8_out + (size_t)g * J_PRE, tt, ln);
    return;
  }

  // Latency-critical main path.
  __builtin_amdgcn_s_setprio(1);

  __shared__ alignas(16) float convb[2][N_NEUR];
  __shared__ uint32_t skb[2][2 * J_MAX];
  __shared__ float fb_lds[20];

  const int s = blockIdx.x;
  const int n = threadIdx.x;

  if (n < 20) fb_lds[n] = basis[19 - n];
  const float bias_n = bias[n];

  // Whole weight row (256 scalars) resident in AGPRs.
  const float4* __restrict__ w4 =
      reinterpret_cast<const float4*>(weight + (size_t)n * N_NEUR);
  FOR64(WDECL)
  FOR64(WLOADPIN)

  const uint32_t idx = (uint32_t)(s * N_NEUR + n);

  float hist[20];
  if (t0 == 0) {
#pragma unroll
    for (int i = 0; i < 20; ++i) hist[i] = 0.0f;
  } else {
#pragma unroll
    for (int i = 0; i < 20; ++i) hist[i] = histws[i * LANES + idx];
  }

  const size_t plane = (size_t)N_SAMP * T_BINS * N_NEUR;
  float* __restrict__ out_spk = out + 0 * plane + (size_t)s * T_BINS * N_NEUR + n;
  float* __restrict__ out_cnv = out + 1 * plane + (size_t)s * T_BINS * N_NEUR + n;
  float* __restrict__ out_rte = out + 2 * plane + (size_t)s * T_BINS * N_NEUR + n;

  uint32_t skreg = 0;
  float4 sc0, sc1;
  if constexpr (MODE == 0) {
    if (n < 2 * J_MAX) skreg = sub[(size_t)t0 * (2 * J_MAX) + n];
  } else {
    const float4* p = reinterpret_cast<const float4*>(S8_in + (size_t)idx * J_PRE);
    sc0 = p[0]; sc1 = p[1];
  }

  __syncthreads();  // fb_lds visible

  // fb in registers (static indices -> VGPRs).
  float fbr[20];
#pragma unroll
  for (int w = 0; w < 20; ++w) fbr[w] = fb_lds[w];

  // conv for step t0: full ascending-w chain (bit-exact prologue).
  float conv = 0.0f;
#pragma unroll
  for (int w = 0; w < 20; ++w) {
#if CONV_FMA
    conv = __builtin_fmaf(fbr[w], hist[w], conv);
#else
    conv = fadd_s(conv, fmul_s(fbr[w], hist[w]));
#endif
  }

  for (int t = t0; t < t1; ++t) {
    const int buf = t & 1;
    float* __restrict__ convbuf = convb[buf];
    const float4* __restrict__ convbuf4 = reinterpret_cast<const float4*>(convbuf);

    const float conv_cur = conv;     // this step's conv (computed last step)
    convbuf[n] = conv_cur;

    float4 sn0, sn1;
    if constexpr (MODE == 0) {
      uint32_t* __restrict__ skbuf = skb[buf];
      if (n < 2 * J_MAX) {
        skbuf[n] = skreg;
        const int tn = (t + 1 < t1) ? t + 1 : t;
        skreg = sub[(size_t)tn * (2 * J_MAX) + n];
      }
    } else {
      const int tn = (t + 1 < t1) ? t + 1 : t;
      const float4* p = reinterpret_cast<const float4*>(
          S8_in + ((size_t)(tn - t0) * LANES + idx) * J_PRE);
      sn0 = p[0]; sn1 = p[1];
    }

#if RAW_BARRIER
    asm volatile("s_waitcnt lgkmcnt(0)\n\ts_barrier" ::: "memory");
#else
    __syncthreads();
#endif

    // Next step's conv prefix (w=0..18 over hist[1..19], all known now).
    float cp = 0.0f;
#pragma unroll
    for (int w = 0; w < 19; ++w) {
#if CONV_FMA
      cp = __builtin_fmaf(fbr[w], hist[w + 1], cp);
#else
      cp = fadd_s(cp, fmul_s(fbr[w], hist[w + 1]));
#endif
    }

    // z = sum_k conv[k]*W[n][k], fused FMA ascending k (order bit-locked).
    float zacc = 0.0f;
    {
      float4 cvA0, cvA1, cvA2, cvA3, cvA4, cvA5, cvA6, cvA7;
      float4 cvB0, cvB1, cvB2, cvB3, cvB4, cvB5, cvB6, cvB7;
      ZLOAD_A(0,1,2,3,4,5,6,7)
      ZLOAD_B(8,9,10,11,12,13,14,15)   ZCOMP_A(0,1,2,3,4,5,6,7)
      ZLOAD_A(16,17,18,19,20,21,22,23) ZCOMP_B(8,9,10,11,12,13,14,15)
      ZLOAD_B(24,25,26,27,28,29,30,31) ZCOMP_A(16,17,18,19,20,21,22,23)
      ZLOAD_A(32,33,34,35,36,37,38,39) ZCOMP_B(24,25,26,27,28,29,30,31)
      ZLOAD_B(40,41,42,43,44,45,46,47) ZCOMP_A(32,33,34,35,36,37,38,39)
      ZLOAD_A(48,49,50,51,52,53,54,55) ZCOMP_B(40,41,42,43,44,45,46,47)
      ZLOAD_B(56,57,58,59,60,61,62,63) ZCOMP_A(48,49,50,51,52,53,54,55)
      ZCOMP_B(56,57,58,59,60,61,62,63)
    }
    const float zb = fadd_s(zacc, bias_n);

    // lam = 1 / (1 + exp(-z))
    const float lam = 1.0f / fadd_s(1.0f, xla_expf(-zb));
    const float neg_lam = -lam;

    int r = 0;
    if constexpr (MODE == 1) {
      // S_j strictly non-increasing -> consecutive-count == count-all.
      r = (sc0.x > neg_lam) + (sc0.y > neg_lam) + (sc0.z > neg_lam) +
          (sc0.w > neg_lam) + (sc1.x > neg_lam) + (sc1.y > neg_lam) +
          (sc1.z > neg_lam) + (sc1.w > neg_lam);
      if (__builtin_expect(sc1.w > neg_lam, 0)) {  // rare: continue chain
        float S = sc1.w;
#pragma unroll 1
        for (int j = J_PRE; j < J_MAX; ++j) {
          const uint32_t k0 = sub[(size_t)t * (2 * J_MAX) + 2 * j];
          const uint32_t k1 = sub[(size_t)t * (2 * J_MAX) + 2 * j + 1];
          uint32_t o0, o1;
          threefry2x32(k0, k1, 0u, idx, o0, o1);
#if BITS32_XOR
          const uint32_t bits = o0 ^ o1;
#else
          const uint32_t bits = o1;
#endif
          const float u = __uint_as_float((bits >> 9) | 0x3f800000u) - 1.0f;
          S = fadd_s(S, xla_logf(u));
          if (S > neg_lam) ++r; else break;
        }
      }
    } else {
      uint32_t* __restrict__ skbuf = skb[buf];
      float S = 0.0f;
      bool done = false;
#pragma unroll 1
      for (int jb = 0; jb < J_MAX; jb += POISSON_BATCH) {
        float L[POISSON_BATCH];
#pragma unroll
        for (int q = 0; q < POISSON_BATCH; ++q) {
          const int j = jb + q;
          uint32_t o0, o1;
          threefry2x32(skbuf[2 * j], skbuf[2 * j + 1], 0u, idx, o0, o1);
#if BITS32_XOR
          const uint32_t bits = o0 ^ o1;
#else
          const uint32_t bits = o1;
#endif
          const float u = __uint_as_float((bits >> 9) | 0x3f800000u) - 1.0f;
          L[q] = xla_logf(u);
        }
#pragma unroll
        for (int q = 0; q < POISSON_BATCH; ++q) {
          if (!done) {
            S = fadd_s(S, L[q]);
            if (S > neg_lam) ++r; else done = true;
          }
        }
        if (__all(done)) break;
      }
    }
    const float spk = (float)r;

#pragma unroll
    for (int i = 0; i < 19; ++i) hist[i] = hist[i + 1];
    hist[19] = spk;

    // Next step's conv: prefix + last term (bit-identical composition).
    conv = fadd_s(cp, fmul_s(fbr[19], spk));

    const size_t off = (size_t)t * N_NEUR;
#if NT_STORES
    __builtin_nontemporal_store(spk,      out_spk + off);
    __builtin_nontemporal_store(conv_cur, out_cnv + off);
    __builtin_nontemporal_store(lam,      out_rte + off);
#else
    out_spk[off] = spk;
    out_cnv[off] = conv_cur;
    out_rte[off] = lam;
#endif
    if constexpr (MODE == 1) { sc0 = sn0; sc1 = sn1; }
#if !RAW_BARRIER
    __syncthreads();
#endif
  }

  // Chunk handoff: persist hist for the next launch.
  if (t1 < T_BINS) {
#pragma unroll
    for (int i = 0; i < 20; ++i) histws[i * LANES + idx] = hist[i];
  }
}

extern "C" void kernel_launch(void* const* d_in, const int* in_sizes, int n_in,
                              void* d_out, int out_size, void* d_ws, size_t ws_size,
                              hipStream_t stream) {
  const float* basis  = (const float*)d_in[0];
  const float* weight = (const float*)d_in[1];
  const float* bias   = (const float*)d_in[2];
  float* out = (float*)d_out;
  char* ws = (char*)d_ws;
  uint32_t* sub = (uint32_t*)ws;
  float* histws = (float*)(ws + HIST_OFF);

  hipLaunchKernelGGL(poglm_subkeys, dim3((T_BINS + 255) / 256), dim3(256), 0,
                     stream, sub);

  // Pick chunkT for DOUBLE-buffered S-table.
  int chunkT = 0;
  const int cand[4] = {256, 512, 128, 64};
  for (int ci = 0; ci < 4; ++ci) {
    const size_t bytes = (size_t)cand[ci] * LANES * J_PRE * 4;
    if (STBL_OFF + 2 * bytes <= ws_size) { chunkT = cand[ci]; break; }
  }

  if (chunkT == 0) {
    int sc = 0;
    for (int c = T_BINS; c >= 64; c >>= 1) {
      const size_t bytes = (size_t)c * LANES * J_PRE * 4;
      if (STBL_OFF + bytes <= ws_size) { sc = c; break; }
    }
    if (sc == 0) {
      hipLaunchKernelGGL((poglm_fused<0>), dim3(N_SAMP), dim3(256), 0,
                         stream, basis, weight, bias, sub, out,
                         (const float*)nullptr, (float*)nullptr, 0,
                         histws, 0, T_BINS);
      return;
    }
    float* stbl = (float*)(ws + STBL_OFF);
    for (int t0 = 0; t0 < T_BINS; t0 += sc) {
      hipLaunchKernelGGL(poglm_stable, dim3(sc * (LANES / 256)), dim3(256), 0,
                         stream, sub, stbl, t0);
      hipLaunchKernelGGL((poglm_fused<1>), dim3(N_SAMP), dim3(256), 0,
                         stream, basis, weight, bias, sub, out,
                         (const float*)stbl, (float*)nullptr, 0,
                         histws, t0, t0 + sc);
    }
    return;
  }

  const size_t stbl_bytes = (size_t)chunkT * LANES * J_PRE * 4;
  float* stbl0 = (float*)(ws + STBL_OFF);
  float* stbl1 = (float*)(ws + STBL_OFF + stbl_bytes);
  const int nstb = chunkT * (LANES / 256);
  const int nc = T_BINS / chunkT;

  hipLaunchKernelGGL(poglm_stable, dim3(nstb), dim3(256), 0, stream,
                     sub, stbl0, 0);

  for (int c = 0; c < nc; ++c) {
    const int t0 = c * chunkT, t1 = t0 + chunkT;
    float* cur = (c & 1) ? stbl1 : stbl0;
    float* nxt = (c & 1) ? stbl0 : stbl1;
    const bool more = (c + 1 < nc);
    hipLaunchKernelGGL((poglm_fused<1>),
                       dim3(N_SAMP + (more ? nstb : 0)), dim3(256), 0,
                       stream, basis, weight, bias, sub, out,
                       (const float*)cur, nxt, t1, histws, t0, t1);
  }
}